// Round 9
// baseline (347.348 us; speedup 1.0000x reference)
//
#include <hip/hip_runtime.h>
#include <cfloat>
#include <climits>

// Problem constants: x (16,2048,256) fp32 -> N=32768 rows; weight (4096,256) fp32.
constexpr int E  = 256;    // quantizing_dim
constexpr int Qn = 4096;   // num_quantizing
constexpr float WSCALE = 4096.0f;   // 2^12 exact pow2 (keeps f16 products well-scaled)

// Round 20: r18 (83us best) + block-level TLP. r19 (counted vmcnt, 4 slots)
// regressed 83->88: intra-block schedule levers are dead (3rd falsification).
// r18's wall (6.2k cyc/tile) is 2.3x its max pipe (LDS 2.7k) -- the residual
// is each wave's serial chain (ds_read->MFMA->retention->barrier) with only
// 2 waves/SIMD in ONE barrier domain: a stage-drain stalls the whole CU.
// Fix: halve LDS to 64KB (2 slots x 32KB half-K tiles) and split the cw axis
// across blocks: grid (2, N/128), each block streams 2048 cw = 32 half-steps.
// 2 blocks/CU = 4 waves/SIMD in two INDEPENDENT barrier domains -- block A's
// drain overlaps block B's MFMAs. launch_bounds(512,4) caps VGPR at 128
// (r18 measured 124, same register content). Numerics: k-halves of each
// cw-tile processed consecutively in the same (kt,s) order into the same acc
// -> bit-identical keys; retention finer (top-2 per 4-tile quarter per ch);
// finalize merges 8 candidates by key -> top-4 -> verbatim exact rescore.

typedef _Float16 half8  __attribute__((ext_vector_type(8)));
typedef _Float16 half4v __attribute__((ext_vector_type(4)));
typedef float    f32x16 __attribute__((ext_vector_type(16)));

#define GAS __attribute__((address_space(1)))
#define LAS __attribute__((address_space(3)))

#define NEG_INF __int_as_float(0xFF800000)

__device__ inline bool lexlt(float a, int ai, float b, int bi) {
    return a < b || (a == b && ai < bi);
}

// ---------------------------------------------------------------------------
// Prep: one 64-lane wave per row (x and w). Emits f16 operand; sumsq only for w.
// (unchanged, validated)
// ---------------------------------------------------------------------------
__global__ __launch_bounds__(256) void prep_kernel(
    const float* __restrict__ x, const float* __restrict__ w,
    _Float16* __restrict__ A16, _Float16* __restrict__ B16,
    float* __restrict__ w2, int nxblocks)
{
    int blk  = blockIdx.x;
    int sub  = threadIdx.x >> 6;
    int lane = threadIdx.x & 63;
    bool isX = blk < nxblocks;
    int row  = (isX ? blk : blk - nxblocks) * 4 + sub;

    const float* src = isX ? x : w;
    float4 v = *(const float4*)(src + (size_t)row * E + lane * 4);

    if (!isX) {
        float s = v.x * v.x + v.y * v.y + v.z * v.z + v.w * v.w;   // UNSCALED sumsq
        #pragma unroll
        for (int off = 32; off; off >>= 1) s += __shfl_xor(s, off);
        if (lane == 0) w2[row] = s;
    }

    float sc = isX ? 1.0f : WSCALE;                            // exact pow2
    half4v h = { (_Float16)(v.x * sc), (_Float16)(v.y * sc),
                 (_Float16)(v.z * sc), (_Float16)(v.w * sc) };
    _Float16* dst16 = (isX ? A16 : B16) + (size_t)row * 256;
    *(half4v*)(dst16 + lane * 4) = h;
}

// ---------------------------------------------------------------------------
// Main MFMA kernel: block = 128 x-rows x 2048 codewords (16 cw-tiles of 128,
// streamed as 32 half-K steps of 32KB), 512 threads (8 waves = 4 cwg x 2 rg),
// grid (2, N/128) -> 512 blocks, 2 blocks/CU. X in registers; 2 LDS slots,
// stage-early + __syncthreads (r18-validated schedule).
// ---------------------------------------------------------------------------
__device__ inline void ins4max(float K[4], float k) {
    #pragma unroll
    for (int t = 0; t < 4; ++t) {            // keep K descending
        float mx = fmaxf(K[t], k);
        k = fminf(K[t], k);
        K[t] = mx;
    }
}

union SmemU {
    _Float16 buf[2][2][128][64];    // [slot][ktl][row][64 f16] = 2 x 32 KB
    float2 mergeS[128 * 16];        // 16 KB overlay: [row][cwg*4 + q]
};

// one K-half step; H is a literal 0/1 (rule #20: xf indices static)
#define KSTEP(T, Q, H)                                                     \
  {                                                                        \
    const int t_ = (T);                                                    \
    if (t_ + 1 < 32) stage_t(t_ + 1);                                      \
    const _Float16* Wb = &sm.buf[t_ & 1][0][0][0];                         \
    if ((H) == 0) { acc0 = (f32x16){}; acc1 = (f32x16){}; }                \
    __builtin_amdgcn_s_setprio(1);                                         \
    _Pragma("unroll")                                                      \
    for (int ktl = 0; ktl < 2; ++ktl)                                      \
      _Pragma("unroll")                                                    \
      for (int s = 0; s < 4; ++s) {                                        \
        int kc = 2 * s + lh;                                               \
        half8 wf = *(const half8*)(Wb + ktl * 8192                         \
                      + fr * 64 + ((kc ^ frsw) << 3));                     \
        acc0 = __builtin_amdgcn_mfma_f32_32x32x16_f16(                     \
                   wf, xf[0][2 * (H) + ktl][s], acc0, 0, 0, 0);            \
        acc1 = __builtin_amdgcn_mfma_f32_32x32x16_f16(                     \
                   wf, xf[1][2 * (H) + ktl][s], acc1, 0, 0, 0);            \
      }                                                                    \
    __builtin_amdgcn_s_setprio(0);                                         \
    if ((H) == 1) {                                                        \
      const int ct_ = t_ >> 1;                                             \
      _Pragma("unroll")                                                    \
      for (int r = 0; r < 16; ++r) {                                       \
        int crow = (r & 3) + 8 * (r >> 2) + 4 * lh;                        \
        int qg   = cwbase + ct_ * 128 + cwg * 32 + crow;                   \
        float pk0 = __int_as_float(                                        \
            (__float_as_int(acc0[r]) & 0xFFFFF000) | qg);                  \
        t2[0][(Q)] = __builtin_amdgcn_fmed3f(t1[0][(Q)], t2[0][(Q)], pk0); \
        t1[0][(Q)] = fmaxf(t1[0][(Q)], pk0);                               \
        float pk1 = __int_as_float(                                        \
            (__float_as_int(acc1[r]) & 0xFFFFF000) | qg);                  \
        t2[1][(Q)] = __builtin_amdgcn_fmed3f(t1[1][(Q)], t2[1][(Q)], pk1); \
        t1[1][(Q)] = fmaxf(t1[1][(Q)], pk1);                               \
      }                                                                    \
    }                                                                      \
    __syncthreads();                                                       \
  }

__global__ __launch_bounds__(512, 4) void vq_mfma_kernel(
    const _Float16* __restrict__ A16,      // (N, 256)  xh
    const _Float16* __restrict__ B16,      // (Qn, 256) wh_s
    float4* __restrict__ top4)             // (N, 2) packed {k0..k3} desc
{
    __shared__ SmemU sm;

    const int tid  = threadIdx.x;
    const int wv   = tid >> 6;           // 0..7
    const int lane = tid & 63;
    const int l31  = lane & 31;
    const int lh   = lane >> 5;          // k-half select
    const int ch   = blockIdx.x;         // codeword half (0/1): 2048 cw
    const int rb   = blockIdx.y;         // x-row band (128 rows)

    const int cwg = wv & 3;              // cw group within tile: cwg*32
    const int rg  = wv >> 2;             // row group: rg*64
    const int cwbase = ch * 2048;

    const int srow = lane >> 3;
    const int schk = lane & 7;

    const _Float16* Ab16 = A16 + (size_t)rb * 128 * 256;
    const _Float16* B16h = B16 + (size_t)ch * 2048 * 256;

    // Stage K-half h of a 128-row operand block into slot. Linear dest per
    // 8-row group (gload_lds constraint); chunk swizzle in the pre-swizzled
    // GLOBAL source (rule #21 involution). 4 gload_lds per thread.
    auto stage_half = [&](const _Float16* src, int slot, int h) {
        #pragma unroll
        for (int ktl = 0; ktl < 2; ++ktl)
            #pragma unroll
            for (int i = 0; i < 2; ++i) {
                int row  = i * 64 + wv * 8 + srow;
                int gchk = schk ^ (row & 7);
                const _Float16* g = src + (size_t)row * 256
                                    + (2 * h + ktl) * 64 + gchk * 8;
                __builtin_amdgcn_global_load_lds((const GAS void*)g,
                    (LAS void*)(&sm.buf[slot][ktl][i * 64 + wv * 8][0]),
                    16, 0, 0);
            }
    };
    // W half-step t: ct = t>>1 (cw tile), h = t&1 (k-half), slot = t&1
    auto stage_t = [&](int t) {
        stage_half(B16h + (size_t)(t >> 1) * 128 * 256, t & 1, t & 1);
    };

    // ---- prologue: bounce X through both slots, load xf registers ----
    stage_half(Ab16, 0, 0);                // slot0 = X kt{0,1}
    stage_half(Ab16, 1, 1);                // slot1 = X kt{2,3}
    __syncthreads();

    half8 xf[2][4][4];                     // [n][kt][s]
    #pragma unroll
    for (int n = 0; n < 2; ++n)
        #pragma unroll
        for (int kt = 0; kt < 4; ++kt)
            #pragma unroll
            for (int s = 0; s < 4; ++s) {
                int xr = rg * 64 + n * 32 + l31;
                int kc = 2 * s + lh;
                xf[n][kt][s] = *(const half8*)(&sm.buf[kt >> 1][kt & 1][0][0]
                                + xr * 64 + ((kc ^ (xr & 7)) << 3));
            }
    __syncthreads();                       // xf in regs -> slots free

    // running retention: per lane, top-2 per (n, quarter = 4 cw-tiles)
    float t1[2][4], t2[2][4];
    #pragma unroll
    for (int n = 0; n < 2; ++n)
        #pragma unroll
        for (int q = 0; q < 4; ++q) { t1[n][q] = NEG_INF; t2[n][q] = NEG_INF; }

    const int fr   = cwg * 32 + l31;       // wave's W frag row within tile
    const int frsw = fr & 7;

    f32x16 acc0, acc1;

    // ---- 32-half-step loop (16 cw-tiles x 2 k-halves) ----
    stage_t(0);
    __syncthreads();                       // step-0 tile staged

    #pragma unroll
    for (int q = 0; q < 4; ++q)
        #pragma unroll
        for (int ctt = 0; ctt < 4; ++ctt) {
            const int t0 = (q * 4 + ctt) * 2;
            KSTEP(t0,     q, 0);
            KSTEP(t0 + 1, q, 1);
        }

    // ---- merge: lh-pair shuffle, then 16 slots/row in LDS, then top-4 ----
    #pragma unroll
    for (int n = 0; n < 2; ++n)
        #pragma unroll
        for (int q = 0; q < 4; ++q) {
            float o1 = __shfl_xor(t1[n][q], 32);
            float o2 = __shfl_xor(t2[n][q], 32);
            float m1 = fmaxf(t1[n][q], o1);
            float m2 = __builtin_amdgcn_fmed3f(t1[n][q], o1,
                                               fmaxf(t2[n][q], o2));
            t1[n][q] = m1; t2[n][q] = m2;  // merged top-2 of the lane pair
        }

    // (final KSTEP ended with __syncthreads -> all tile reads done)
    if (lh == 0) {
        #pragma unroll
        for (int n = 0; n < 2; ++n) {
            int row = rg * 64 + n * 32 + l31;
            #pragma unroll
            for (int q = 0; q < 4; ++q)
                sm.mergeS[row * 16 + cwg * 4 + q] =
                    make_float2(t1[n][q], t2[n][q]);
        }
    }
    __syncthreads();

    if (tid < 128) {
        float K[4] = { NEG_INF, NEG_INF, NEG_INF, NEG_INF };
        #pragma unroll
        for (int sl = 0; sl < 16; ++sl) {
            float2 a = sm.mergeS[tid * 16 + sl];
            ins4max(K, a.x);
            ins4max(K, a.y);
        }
        top4[((size_t)rb * 128 + tid) * 2 + ch] =
            make_float4(K[0], K[1], K[2], K[3]);
    }
}

// ---------------------------------------------------------------------------
// Finalize: per row, 2 x top-4 packed candidates (one per cw-half) -> top-4
// by packed key -> exact fp32 rescore (reference formula + first-index
// tie-break), write outputs. Rescore math verbatim from validated kernel.
// ---------------------------------------------------------------------------
__global__ __launch_bounds__(256) void finalize_kernel(
    const float4* __restrict__ top4, const float* __restrict__ x,
    const float* __restrict__ w, const float* __restrict__ w2,
    float* __restrict__ qdata, float* __restrict__ qidx)
{
    int row  = blockIdx.x * 4 + (threadIdx.x >> 6);
    int lane = threadIdx.x & 63;

    float4 a = top4[(size_t)row * 2 + 0];
    float4 b = top4[(size_t)row * 2 + 1];
    float K[4] = { NEG_INF, NEG_INF, NEG_INF, NEG_INF };
    ins4max(K, a.x); ins4max(K, a.y); ins4max(K, a.z); ins4max(K, a.w);
    ins4max(K, b.x); ins4max(K, b.y); ins4max(K, b.z); ins4max(K, b.w);

    int chosen[4] = { __float_as_int(K[0]) & 0xFFF,
                      __float_as_int(K[1]) & 0xFFF,
                      __float_as_int(K[2]) & 0xFFF,
                      __float_as_int(K[3]) & 0xFFF };

    // exact fp32 rescore of the 4 survivors (round-1-validated formula);
    // X2 via the same data layout + butterfly order as the validated prep.
    float4 xv = *(const float4*)(x + (size_t)row * E + lane * 4);
    float s2 = xv.x * xv.x + xv.y * xv.y + xv.z * xv.z + xv.w * xv.w;
    float d[4];
    #pragma unroll
    for (int j = 0; j < 4; ++j) {
        float4 wv = *(const float4*)(w + (size_t)chosen[j] * E + lane * 4);
        d[j] = xv.x * wv.x + xv.y * wv.y + xv.z * wv.z + xv.w * wv.w;
    }
    #pragma unroll
    for (int off = 32; off; off >>= 1) {
        s2 += __shfl_xor(s2, off);
        #pragma unroll
        for (int j = 0; j < 4; ++j) d[j] += __shfl_xor(d[j], off);
    }

    float bs = FLT_MAX; int win = INT_MAX;
    #pragma unroll
    for (int j = 0; j < 4; ++j) {
        float s = (s2 - 2.0f * d[j]) + w2[chosen[j]];
        if (lexlt(s, chosen[j], bs, win)) { bs = s; win = chosen[j]; }
    }

    if (lane == 0) qidx[row] = (float)win;
    *(float4*)(qdata + (size_t)row * E + lane * 4) =
        *(const float4*)(w + (size_t)win * E + lane * 4);
}

// ---------------------------------------------------------------------------
// Round-1 fp32 fallback (only if ws_size too small). Passed absmax 0.
// ---------------------------------------------------------------------------
constexpr int FBM = 64, FBN = 128, FBK = 64, FPAD = 4, FTH = 256;

__global__ __launch_bounds__(64) void row_sumsq_kernel(const float* __restrict__ src,
                                                       float* __restrict__ dst) {
    int row = blockIdx.x, lane = threadIdx.x;
    float4 v = ((const float4*)(src + (size_t)row * E))[lane];
    float s = v.x * v.x + v.y * v.y + v.z * v.z + v.w * v.w;
    #pragma unroll
    for (int off = 32; off > 0; off >>= 1) s += __shfl_down(s, off);
    if (lane == 0) dst[row] = s;
}

__global__ __launch_bounds__(FTH) void vq_fallback_kernel(
    const float* __restrict__ x, const float* __restrict__ w,
    const float* __restrict__ x2, const float* __restrict__ w2,
    float* __restrict__ qdata, float* __restrict__ qidx)
{
    __shared__ float xs[FBM][FBK + FPAD];
    __shared__ float ws[FBN][FBK + FPAD];
    __shared__ float redS[FBM][16];
    __shared__ int   redC[FBM][16];
    __shared__ int   bestC[FBM];

    const int tid = threadIdx.x, tr = tid >> 4, tc = tid & 15;
    const int r0 = blockIdx.x * FBM;
    float best[4]; int bidx[4];
    #pragma unroll
    for (int i = 0; i < 4; ++i) { best[i] = FLT_MAX; bidx[i] = 0x7FFFFFFF; }
    float x2r[4];
    #pragma unroll
    for (int i = 0; i < 4; ++i) x2r[i] = x2[r0 + tr + 16 * i];

    for (int qt = 0; qt < Qn / FBN; ++qt) {
        const int c0 = qt * FBN;
        float acc[4][8];
        #pragma unroll
        for (int i = 0; i < 4; ++i)
            #pragma unroll
            for (int j = 0; j < 8; ++j) acc[i][j] = 0.f;
        for (int kt = 0; kt < E / FBK; ++kt) {
            __syncthreads();
            const int kk = (tid & 15) * 4, rr = tid >> 4;
            #pragma unroll
            for (int m = 0; m < 4; ++m)
                *(float4*)&xs[m * 16 + rr][kk] =
                    *(const float4*)(x + (size_t)(r0 + m * 16 + rr) * E + kt * FBK + kk);
            #pragma unroll
            for (int m = 0; m < 8; ++m)
                *(float4*)&ws[m * 16 + rr][kk] =
                    *(const float4*)(w + (size_t)(c0 + m * 16 + rr) * E + kt * FBK + kk);
            __syncthreads();
            #pragma unroll
            for (int k4 = 0; k4 < FBK / 4; ++k4) {
                float4 a[4], bb[8];
                #pragma unroll
                for (int i = 0; i < 4; ++i) a[i] = *(const float4*)&xs[tr + 16 * i][k4 * 4];
                #pragma unroll
                for (int j = 0; j < 8; ++j) bb[j] = *(const float4*)&ws[tc + 16 * j][k4 * 4];
                #pragma unroll
                for (int i = 0; i < 4; ++i)
                    #pragma unroll
                    for (int j = 0; j < 8; ++j) {
                        acc[i][j] += a[i].x * bb[j].x; acc[i][j] += a[i].y * bb[j].y;
                        acc[i][j] += a[i].z * bb[j].z; acc[i][j] += a[i].w * bb[j].w;
                    }
            }
        }
        #pragma unroll
        for (int i = 0; i < 4; ++i)
            #pragma unroll
            for (int j = 0; j < 8; ++j) {
                int c = c0 + tc + 16 * j;
                float s = (x2r[i] - 2.0f * acc[i][j]) + w2[c];
                if (s < best[i]) { best[i] = s; bidx[i] = c; }
            }
    }
    #pragma unroll
    for (int i = 0; i < 4; ++i) { redS[tr + 16 * i][tc] = best[i]; redC[tr + 16 * i][tc] = bidx[i]; }
    __syncthreads();
    if (tid < FBM) {
        float bs = FLT_MAX; int bc = 0x7FFFFFFF;
        #pragma unroll
        for (int t = 0; t < 16; ++t) {
            float s = redS[tid][t]; int c = redC[tid][t];
            if (s < bs || (s == bs && c < bc)) { bs = s; bc = c; }
        }
        qidx[r0 + tid] = (float)bc; bestC[tid] = bc;
    }
    __syncthreads();
    for (int it = 0; it < FBM / 4; ++it) {
        int row = it * 4 + (tid >> 6), c = bestC[row], kk = (tid & 63) * 4;
        *(float4*)(qdata + (size_t)(r0 + row) * E + kk) = *(const float4*)(w + (size_t)c * E + kk);
    }
}

// ---------------------------------------------------------------------------
extern "C" void kernel_launch(void* const* d_in, const int* in_sizes, int n_in,
                              void* d_out, int out_size, void* d_ws, size_t ws_size,
                              hipStream_t stream) {
    const float* x = (const float*)d_in[0];
    const float* w = (const float*)d_in[1];
    const int N = in_sizes[0] / E;                      // 32768

    float* qdata = (float*)d_out;
    float* qidx  = (float*)d_out + (size_t)N * E;

    size_t off = 0;
    auto carve = [&](size_t bytes) { size_t p = off; off += (bytes + 255) & ~(size_t)255; return p; };
    size_t oA16 = carve((size_t)N  * 256 * sizeof(_Float16));     // 16.8 MB
    size_t oB16 = carve((size_t)Qn * 256 * sizeof(_Float16));     //  2.1 MB
    size_t ow2  = carve((size_t)Qn * sizeof(float));
    size_t oT   = carve((size_t)N * 2 * sizeof(float4));          // 1 MB
    size_t ox2f = carve((size_t)N * sizeof(float));               // fallback only

    if (ws_size >= off && (N % 128) == 0) {
        char* ws = (char*)d_ws;
        _Float16* A16 = (_Float16*)(ws + oA16);
        _Float16* B16 = (_Float16*)(ws + oB16);
        float* w2    = (float*)(ws + ow2);
        float4* top4 = (float4*)(ws + oT);

        prep_kernel<<<N / 4 + Qn / 4, 256, 0, stream>>>(x, w, A16, B16, w2, N / 4);
        vq_mfma_kernel<<<dim3(2, N / 128), 512, 0, stream>>>(A16, B16, top4);
        finalize_kernel<<<N / 4, 256, 0, stream>>>(top4, x, w, w2, qdata, qidx);
    } else {
        float* x2 = (float*)d_ws;
        float* w2 = x2 + N;
        row_sumsq_kernel<<<N, 64, 0, stream>>>(x, x2);
        row_sumsq_kernel<<<Qn, 64, 0, stream>>>(w, w2);
        vq_fallback_kernel<<<N / FBM, FTH, 0, stream>>>(x, w, x2, w2, qdata, qidx);
    }
}

// Round 10
// 177.899 us; speedup vs baseline: 1.9525x; 1.9525x over previous
//
#include <hip/hip_runtime.h>
#include <cfloat>
#include <climits>

// Problem constants: x (16,2048,256) fp32 -> N=32768 rows; weight (4096,256) fp32.
constexpr int E  = 256;    // quantizing_dim
constexpr int Qn = 4096;   // num_quantizing
constexpr float WSCALE = 4096.0f;   // 2^12 exact pow2 (keeps f16 products well-scaled)

// Round 21 = verbatim revert to round 18 (vq 83.0us, total ~177us, absmax 0
// -- the session's validated best). Round-20 post-mortem: launch_bounds(512,4)
// capped combined VGPR+AGPR at 128 < xf's 128 + acc -> X fragments spilled to
// scratch (VGPR_Count 64, FETCH 646MB, vq 253us). Structural conclusion: the
// X-in-regs design (the only variant to beat 92us) requires ~250 combined
// regs/wave -> 2 waves/SIMD is a hard ceiling; all schedule levers (T3 x1,
// T4 x2), tile/acc reshapes (x2), barrier-free W-resident, fused finalize,
// and block-TLP have been individually falsified on this kernel. r18 is the
// local optimum: block = 128 x-rows x all 4096 codewords, grid = N/128 = 256
// (1 block/CU); X (64 rows x K256 per wave = 32 half8) loaded once via LDS
// bounce, resident in registers; W streamed as 32 x 64KB tiles through 2 LDS
// slots with stage-early + __syncthreads; fr&7 chunk-swizzle staging
// involution; packed-key top-2 retention per 8-tile quarter; exact fp32
// rescore in finalize.

typedef _Float16 half8  __attribute__((ext_vector_type(8)));
typedef _Float16 half4v __attribute__((ext_vector_type(4)));
typedef float    f32x16 __attribute__((ext_vector_type(16)));

#define GAS __attribute__((address_space(1)))
#define LAS __attribute__((address_space(3)))

#define NEG_INF __int_as_float(0xFF800000)

__device__ inline bool lexlt(float a, int ai, float b, int bi) {
    return a < b || (a == b && ai < bi);
}

// ---------------------------------------------------------------------------
// Prep: one 64-lane wave per row (x and w). Emits f16 operand; sumsq only for w.
// (unchanged, validated)
// ---------------------------------------------------------------------------
__global__ __launch_bounds__(256) void prep_kernel(
    const float* __restrict__ x, const float* __restrict__ w,
    _Float16* __restrict__ A16, _Float16* __restrict__ B16,
    float* __restrict__ w2, int nxblocks)
{
    int blk  = blockIdx.x;
    int sub  = threadIdx.x >> 6;
    int lane = threadIdx.x & 63;
    bool isX = blk < nxblocks;
    int row  = (isX ? blk : blk - nxblocks) * 4 + sub;

    const float* src = isX ? x : w;
    float4 v = *(const float4*)(src + (size_t)row * E + lane * 4);

    if (!isX) {
        float s = v.x * v.x + v.y * v.y + v.z * v.z + v.w * v.w;   // UNSCALED sumsq
        #pragma unroll
        for (int off = 32; off; off >>= 1) s += __shfl_xor(s, off);
        if (lane == 0) w2[row] = s;
    }

    float sc = isX ? 1.0f : WSCALE;                            // exact pow2
    half4v h = { (_Float16)(v.x * sc), (_Float16)(v.y * sc),
                 (_Float16)(v.z * sc), (_Float16)(v.w * sc) };
    _Float16* dst16 = (isX ? A16 : B16) + (size_t)row * 256;
    *(half4v*)(dst16 + lane * 4) = h;
}

// ---------------------------------------------------------------------------
// Main MFMA kernel: block = 128 x-rows x all 4096 codewords (32 tiles of 128),
// 512 threads (8 waves = 4 cw-groups x 2 row-groups), grid = N/128 = 256.
// Per wave per tile: 32 cw (M=1) x 64 rows (N=2), 32 MFMAs, 16 ds_reads,
// X operand entirely in registers.
// ---------------------------------------------------------------------------
__device__ inline void ins4max(float K[4], float k) {
    #pragma unroll
    for (int t = 0; t < 4; ++t) {            // keep K descending
        float mx = fmaxf(K[t], k);
        k = fminf(K[t], k);
        K[t] = mx;
    }
}

union SmemU {
    _Float16 buf[2][4][128][64];    // [dbuf][kt][row][64 f16] = 2 x 64 KB
    float2 mergeS[128 * 16];        // 16 KB overlay: [row][cwg*4 + q]
};

__global__ __launch_bounds__(512, 2) void vq_mfma_kernel(
    const _Float16* __restrict__ A16,      // (N, 256)  xh
    const _Float16* __restrict__ B16,      // (Qn, 256) wh_s
    float4* __restrict__ top4)             // (N) packed {k0,k1,k2,k3} desc
{
    __shared__ SmemU sm;

    const int tid  = threadIdx.x;
    const int wv   = tid >> 6;           // 0..7
    const int lane = tid & 63;
    const int l31  = lane & 31;
    const int lh   = lane >> 5;          // k-half select
    const int rb   = blockIdx.x;         // x-row band (128 rows)

    const int cwg = wv & 3;              // cw group within tile: cwg*32
    const int rg  = wv >> 2;             // row group: rg*64

    const _Float16* Ab16 = A16 + (size_t)rb * 128 * 256;

    // Stage one 128-row x K256 operand block into buf[bi], layout
    // [kt][row][64], linear dest per 8-row wave slice; chunk swizzle lives in
    // the pre-swizzled GLOBAL source (rule #21 involution), read side XORs
    // the same (row&7).  8 gload_lds per thread.
    auto stage128 = [&](const _Float16* src, int bi) {
        #pragma unroll
        for (int kt = 0; kt < 4; ++kt)
            #pragma unroll
            for (int i = 0; i < 2; ++i) {
                int row  = i * 64 + wv * 8 + (lane >> 3);
                int gchk = (lane & 7) ^ (row & 7);
                const _Float16* g = src + (size_t)row * 256 + kt * 64 + gchk * 8;
                __builtin_amdgcn_global_load_lds((const GAS void*)g,
                    (LAS void*)(&sm.buf[bi][kt][i * 64 + wv * 8][0]), 16, 0, 0);
            }
    };

    // ---- prologue: bounce X through buf[0], W tile 0 into buf[1] ----
    stage128(Ab16, 0);
    stage128(B16, 1);                      // tile 0 (cw 0..127)
    __syncthreads();                       // both staged

    // X fragments -> registers (validated r12 xf addressing, rows rg*64+..)
    half8 xf[2][4][4];                     // [n][kt][s]
    #pragma unroll
    for (int n = 0; n < 2; ++n)
        #pragma unroll
        for (int kt = 0; kt < 4; ++kt)
            #pragma unroll
            for (int s = 0; s < 4; ++s) {
                int xr = rg * 64 + n * 32 + l31;
                int kc = 2 * s + lh;
                xf[n][kt][s] = *(const half8*)(&sm.buf[0][kt][0][0]
                                + xr * 64 + ((kc ^ (xr & 7)) << 3));
            }
    __syncthreads();                       // X reads done -> buf[0] free

    // running retention: per lane, top-2 per (n, 8-tile quarter)
    float t1[2][4], t2[2][4];
    #pragma unroll
    for (int n = 0; n < 2; ++n)
        #pragma unroll
        for (int q = 0; q < 4; ++q) { t1[n][q] = NEG_INF; t2[n][q] = NEG_INF; }

    const int fr = cwg * 32 + l31;         // wave's W frag row within tile
    const int frsw = fr & 7;

    // ---- 32-tile W loop: stage-early + __syncthreads (r12 schedule) ----
    #pragma unroll
    for (int q = 0; q < 4; ++q) {
        for (int tt = 0; tt < 8; ++tt) {
            const int t  = q * 8 + tt;
            const int bi = (t + 1) & 1;    // tile t lives in buf[(t+1)&1]

            if (t + 1 < 32)                // stage next tile into other buf
                stage128(B16 + (size_t)(t + 1) * 128 * 256, t & 1);

            const _Float16* Wb = &sm.buf[bi][0][0][0];

            f32x16 acc0 = {}, acc1 = {};
            __builtin_amdgcn_s_setprio(1);
            #pragma unroll
            for (int kt = 0; kt < 4; ++kt)
                #pragma unroll
                for (int s = 0; s < 4; ++s) {
                    int kc = 2 * s + lh;
                    half8 wf = *(const half8*)(Wb + kt * 8192
                                  + fr * 64 + ((kc ^ frsw) << 3));
                    acc0 = __builtin_amdgcn_mfma_f32_32x32x16_f16(
                               wf, xf[0][kt][s], acc0, 0, 0, 0);
                    acc1 = __builtin_amdgcn_mfma_f32_32x32x16_f16(
                               wf, xf[1][kt][s], acc1, 0, 0, 0);
                }
            __builtin_amdgcn_s_setprio(0);

            // retire tile t: packed key = (bits & ~0xFFF) | cw ; top-2 update
            #pragma unroll
            for (int r = 0; r < 16; ++r) {
                int crow = (r & 3) + 8 * (r >> 2) + 4 * lh;   // C-row (32x32)
                int qg   = t * 128 + cwg * 32 + crow;         // global cw id
                float pk0 = __int_as_float(
                    (__float_as_int(acc0[r]) & 0xFFFFF000) | qg);
                t2[0][q] = __builtin_amdgcn_fmed3f(t1[0][q], t2[0][q], pk0);
                t1[0][q] = fmaxf(t1[0][q], pk0);
                float pk1 = __int_as_float(
                    (__float_as_int(acc1[r]) & 0xFFFFF000) | qg);
                t2[1][q] = __builtin_amdgcn_fmed3f(t1[1][q], t2[1][q], pk1);
                t1[1][q] = fmaxf(t1[1][q], pk1);
            }

            __syncthreads();               // stage(t+1) landed; buf swap safe
        }
    }

    // ---- merge: lh-pair shuffle, then 16 slots/row in LDS, then top-4 ----
    #pragma unroll
    for (int n = 0; n < 2; ++n)
        #pragma unroll
        for (int q = 0; q < 4; ++q) {
            float o1 = __shfl_xor(t1[n][q], 32);
            float o2 = __shfl_xor(t2[n][q], 32);
            float m1 = fmaxf(t1[n][q], o1);
            float m2 = __builtin_amdgcn_fmed3f(t1[n][q], o1,
                                               fmaxf(t2[n][q], o2));
            t1[n][q] = m1; t2[n][q] = m2;  // merged top-2 of the lane pair
        }

    // (last tile read buf[0]; overlay written only after the loop's final sync)
    if (lh == 0) {
        #pragma unroll
        for (int n = 0; n < 2; ++n) {
            int row = rg * 64 + n * 32 + l31;
            #pragma unroll
            for (int q = 0; q < 4; ++q)
                sm.mergeS[row * 16 + cwg * 4 + q] =
                    make_float2(t1[n][q], t2[n][q]);
        }
    }
    __syncthreads();

    if (tid < 128) {
        float K[4] = { NEG_INF, NEG_INF, NEG_INF, NEG_INF };
        #pragma unroll
        for (int sl = 0; sl < 16; ++sl) {
            float2 a = sm.mergeS[tid * 16 + sl];
            ins4max(K, a.x);
            ins4max(K, a.y);
        }
        top4[(size_t)rb * 128 + tid] = make_float4(K[0], K[1], K[2], K[3]);
    }
}

// ---------------------------------------------------------------------------
// Finalize: per row, 4 packed candidates (already global top-4 by key) ->
// exact fp32 rescore (reference formula + first-index tie-break), write
// outputs. Rescore math verbatim from the validated kernel.
// ---------------------------------------------------------------------------
__global__ __launch_bounds__(256) void finalize_kernel(
    const float4* __restrict__ top4, const float* __restrict__ x,
    const float* __restrict__ w, const float* __restrict__ w2,
    float* __restrict__ qdata, float* __restrict__ qidx)
{
    int row  = blockIdx.x * 4 + (threadIdx.x >> 6);
    int lane = threadIdx.x & 63;

    float4 c4 = top4[row];
    int chosen[4] = { __float_as_int(c4.x) & 0xFFF,
                      __float_as_int(c4.y) & 0xFFF,
                      __float_as_int(c4.z) & 0xFFF,
                      __float_as_int(c4.w) & 0xFFF };

    // exact fp32 rescore of the 4 survivors (round-1-validated formula);
    // X2 via the same data layout + butterfly order as the validated prep.
    float4 xv = *(const float4*)(x + (size_t)row * E + lane * 4);
    float s2 = xv.x * xv.x + xv.y * xv.y + xv.z * xv.z + xv.w * xv.w;
    float d[4];
    #pragma unroll
    for (int j = 0; j < 4; ++j) {
        float4 wv = *(const float4*)(w + (size_t)chosen[j] * E + lane * 4);
        d[j] = xv.x * wv.x + xv.y * wv.y + xv.z * wv.z + xv.w * wv.w;
    }
    #pragma unroll
    for (int off = 32; off; off >>= 1) {
        s2 += __shfl_xor(s2, off);
        #pragma unroll
        for (int j = 0; j < 4; ++j) d[j] += __shfl_xor(d[j], off);
    }

    float bs = FLT_MAX; int win = INT_MAX;
    #pragma unroll
    for (int j = 0; j < 4; ++j) {
        float s = (s2 - 2.0f * d[j]) + w2[chosen[j]];
        if (lexlt(s, chosen[j], bs, win)) { bs = s; win = chosen[j]; }
    }

    if (lane == 0) qidx[row] = (float)win;
    *(float4*)(qdata + (size_t)row * E + lane * 4) =
        *(const float4*)(w + (size_t)win * E + lane * 4);
}

// ---------------------------------------------------------------------------
// Round-1 fp32 fallback (only if ws_size too small). Passed absmax 0.
// ---------------------------------------------------------------------------
constexpr int FBM = 64, FBN = 128, FBK = 64, FPAD = 4, FTH = 256;

__global__ __launch_bounds__(64) void row_sumsq_kernel(const float* __restrict__ src,
                                                       float* __restrict__ dst) {
    int row = blockIdx.x, lane = threadIdx.x;
    float4 v = ((const float4*)(src + (size_t)row * E))[lane];
    float s = v.x * v.x + v.y * v.y + v.z * v.z + v.w * v.w;
    #pragma unroll
    for (int off = 32; off > 0; off >>= 1) s += __shfl_down(s, off);
    if (lane == 0) dst[row] = s;
}

__global__ __launch_bounds__(FTH) void vq_fallback_kernel(
    const float* __restrict__ x, const float* __restrict__ w,
    const float* __restrict__ x2, const float* __restrict__ w2,
    float* __restrict__ qdata, float* __restrict__ qidx)
{
    __shared__ float xs[FBM][FBK + FPAD];
    __shared__ float ws[FBN][FBK + FPAD];
    __shared__ float redS[FBM][16];
    __shared__ int   redC[FBM][16];
    __shared__ int   bestC[FBM];

    const int tid = threadIdx.x, tr = tid >> 4, tc = tid & 15;
    const int r0 = blockIdx.x * FBM;
    float best[4]; int bidx[4];
    #pragma unroll
    for (int i = 0; i < 4; ++i) { best[i] = FLT_MAX; bidx[i] = 0x7FFFFFFF; }
    float x2r[4];
    #pragma unroll
    for (int i = 0; i < 4; ++i) x2r[i] = x2[r0 + tr + 16 * i];

    for (int qt = 0; qt < Qn / FBN; ++qt) {
        const int c0 = qt * FBN;
        float acc[4][8];
        #pragma unroll
        for (int i = 0; i < 4; ++i)
            #pragma unroll
            for (int j = 0; j < 8; ++j) acc[i][j] = 0.f;
        for (int kt = 0; kt < E / FBK; ++kt) {
            __syncthreads();
            const int kk = (tid & 15) * 4, rr = tid >> 4;
            #pragma unroll
            for (int m = 0; m < 4; ++m)
                *(float4*)&xs[m * 16 + rr][kk] =
                    *(const float4*)(x + (size_t)(r0 + m * 16 + rr) * E + kt * FBK + kk);
            #pragma unroll
            for (int m = 0; m < 8; ++m)
                *(float4*)&ws[m * 16 + rr][kk] =
                    *(const float4*)(w + (size_t)(c0 + m * 16 + rr) * E + kt * FBK + kk);
            __syncthreads();
            #pragma unroll
            for (int k4 = 0; k4 < FBK / 4; ++k4) {
                float4 a[4], bb[8];
                #pragma unroll
                for (int i = 0; i < 4; ++i) a[i] = *(const float4*)&xs[tr + 16 * i][k4 * 4];
                #pragma unroll
                for (int j = 0; j < 8; ++j) bb[j] = *(const float4*)&ws[tc + 16 * j][k4 * 4];
                #pragma unroll
                for (int i = 0; i < 4; ++i)
                    #pragma unroll
                    for (int j = 0; j < 8; ++j) {
                        acc[i][j] += a[i].x * bb[j].x; acc[i][j] += a[i].y * bb[j].y;
                        acc[i][j] += a[i].z * bb[j].z; acc[i][j] += a[i].w * bb[j].w;
                    }
            }
        }
        #pragma unroll
        for (int i = 0; i < 4; ++i)
            #pragma unroll
            for (int j = 0; j < 8; ++j) {
                int c = c0 + tc + 16 * j;
                float s = (x2r[i] - 2.0f * acc[i][j]) + w2[c];
                if (s < best[i]) { best[i] = s; bidx[i] = c; }
            }
    }
    #pragma unroll
    for (int i = 0; i < 4; ++i) { redS[tr + 16 * i][tc] = best[i]; redC[tr + 16 * i][tc] = bidx[i]; }
    __syncthreads();
    if (tid < FBM) {
        float bs = FLT_MAX; int bc = 0x7FFFFFFF;
        #pragma unroll
        for (int t = 0; t < 16; ++t) {
            float s = redS[tid][t]; int c = redC[tid][t];
            if (s < bs || (s == bs && c < bc)) { bs = s; bc = c; }
        }
        qidx[r0 + tid] = (float)bc; bestC[tid] = bc;
    }
    __syncthreads();
    for (int it = 0; it < FBM / 4; ++it) {
        int row = it * 4 + (tid >> 6), c = bestC[row], kk = (tid & 63) * 4;
        *(float4*)(qdata + (size_t)(r0 + row) * E + kk) = *(const float4*)(w + (size_t)c * E + kk);
    }
}

// ---------------------------------------------------------------------------
extern "C" void kernel_launch(void* const* d_in, const int* in_sizes, int n_in,
                              void* d_out, int out_size, void* d_ws, size_t ws_size,
                              hipStream_t stream) {
    const float* x = (const float*)d_in[0];
    const float* w = (const float*)d_in[1];
    const int N = in_sizes[0] / E;                      // 32768

    float* qdata = (float*)d_out;
    float* qidx  = (float*)d_out + (size_t)N * E;

    size_t off = 0;
    auto carve = [&](size_t bytes) { size_t p = off; off += (bytes + 255) & ~(size_t)255; return p; };
    size_t oA16 = carve((size_t)N  * 256 * sizeof(_Float16));     // 16.8 MB
    size_t oB16 = carve((size_t)Qn * 256 * sizeof(_Float16));     //  2.1 MB
    size_t ow2  = carve((size_t)Qn * sizeof(float));
    size_t oT   = carve((size_t)N * sizeof(float4));              // 512 KB
    size_t ox2f = carve((size_t)N * sizeof(float));               // fallback only

    if (ws_size >= off && (N % 128) == 0) {
        char* ws = (char*)d_ws;
        _Float16* A16 = (_Float16*)(ws + oA16);
        _Float16* B16 = (_Float16*)(ws + oB16);
        float* w2    = (float*)(ws + ow2);
        float4* top4 = (float4*)(ws + oT);

        prep_kernel<<<N / 4 + Qn / 4, 256, 0, stream>>>(x, w, A16, B16, w2, N / 4);
        vq_mfma_kernel<<<N / 128, 512, 0, stream>>>(A16, B16, top4);
        finalize_kernel<<<N / 4, 256, 0, stream>>>(top4, x, w, w2, qdata, qidx);
    } else {
        float* x2 = (float*)d_ws;
        float* w2 = x2 + N;
        row_sumsq_kernel<<<N, 64, 0, stream>>>(x, x2);
        row_sumsq_kernel<<<Qn, 64, 0, stream>>>(w, w2);
        vq_fallback_kernel<<<N / FBM, FTH, 0, stream>>>(x, w, x2, w2, qdata, qidx);
    }
}